// Round 22
// baseline (72.145 us; speedup 1.0000x reference)
//
#include <hip/hip_runtime.h>
#include <hip/hip_bf16.h>

#define NN 8192
#define DD 256
#define LOG2E 1.4426950408889634f
#define LN2f 0.6931471805599453f

typedef __attribute__((ext_vector_type(8))) short short8;
typedef __attribute__((ext_vector_type(4))) float f32x4;

__device__ __forceinline__ unsigned short f2bf(float x) {
    unsigned int u = __float_as_uint(x);
    u += 0x7fff + ((u >> 16) & 1);
    return (unsigned short)(u >> 16);
}
__device__ __forceinline__ float epsf(float w) {
    return 1.f - 0.9f / (1.f + __expf(-5.f * w));
}

// 512 blocks x 512 thr (8 waves); wave handles 2 rows serially.
// L2-normalize, fold (logit_scale*log2e) into f1n, emit bf16 + fp32 diag,
// zero rse/cse, accumulate S/T in registers, LDS-combine across 8 waves,
// STORE one float4[256] per block (no atomics). Zeroes totalp (block 0).
// [r18/r21-verified, byte-identical]
__global__ __launch_bounds__(512) void nrm_kernel(
    const float* __restrict__ f1, const float* __restrict__ f2,
    const float* __restrict__ scale_p, const float* __restrict__ wts,
    unsigned short* __restrict__ f1n, unsigned short* __restrict__ f2n,
    float* __restrict__ diag, float* __restrict__ rse, float* __restrict__ cse,
    float4* __restrict__ STp, float* __restrict__ totalp)
{
    __shared__ float4 red[8][256];
    const int w = threadIdx.x >> 6, lane = threadIdx.x & 63;
    const float s = scale_p[0];
    const int row0 = blockIdx.x * 16 + w * 2;
    float s1a[4] = {0,0,0,0}, t1a[4] = {0,0,0,0};
    float s2a[4] = {0,0,0,0}, t2a[4] = {0,0,0,0};
#pragma unroll
    for (int r = 0; r < 2; ++r) {
        const int row = row0 + r;
        const float4 a = reinterpret_cast<const float4*>(f1 + (size_t)row * DD)[lane];
        const float4 b = reinterpret_cast<const float4*>(f2 + (size_t)row * DD)[lane];
        float sa = a.x * a.x + a.y * a.y + a.z * a.z + a.w * a.w;
        float sb = b.x * b.x + b.y * b.y + b.z * b.z + b.w * b.w;
        float sab = a.x * b.x + a.y * b.y + a.z * b.z + a.w * b.w;
#pragma unroll
        for (int off = 1; off < 64; off <<= 1) {
            sa += __shfl_xor(sa, off);
            sb += __shfl_xor(sb, off);
            sab += __shfl_xor(sab, off);
        }
        const float n1 = fmaxf(sqrtf(sa), 1e-12f);
        const float n2 = fmaxf(sqrtf(sb), 1e-12f);
        const float e = epsf(wts[row]);
        if (lane == 0) { diag[row] = s * sab / (n1 * n2); rse[row] = 0.f; cse[row] = 0.f; }
        const float r1 = s * LOG2E / n1, r2 = 1.0f / n2;
        const float v0 = a.x * r1, v1 = a.y * r1, v2 = a.z * r1, v3 = a.w * r1;
        const float u0 = b.x * r2, u1 = b.y * r2, u2 = b.z * r2, u3 = b.w * r2;
        ushort4 o1, o2;
        o1.x = f2bf(v0); o1.y = f2bf(v1); o1.z = f2bf(v2); o1.w = f2bf(v3);
        o2.x = f2bf(u0); o2.y = f2bf(u1); o2.z = f2bf(u2); o2.w = f2bf(u3);
        reinterpret_cast<ushort4*>(f1n + (size_t)row * DD)[lane] = o1;
        reinterpret_cast<ushort4*>(f2n + (size_t)row * DD)[lane] = o2;
        s1a[0] += v0; s1a[1] += v1; s1a[2] += v2; s1a[3] += v3;
        t1a[0] += e * v0; t1a[1] += e * v1; t1a[2] += e * v2; t1a[3] += e * v3;
        s2a[0] += u0; s2a[1] += u1; s2a[2] += u2; s2a[3] += u3;
        t2a[0] += e * u0; t2a[1] += e * u1; t2a[2] += e * u2; t2a[3] += e * u3;
    }
#pragma unroll
    for (int k = 0; k < 4; ++k)
        red[w][lane * 4 + k] = make_float4(s1a[k], t1a[k], s2a[k], t2a[k]);
    __syncthreads();
    if (threadIdx.x < 256) {
        const int c = threadIdx.x;
        float4 acc = red[0][c];
#pragma unroll
        for (int q = 1; q < 8; ++q) {
            const float4 v = red[q][c];
            acc.x += v.x; acc.y += v.y; acc.z += v.z; acc.w += v.w;
        }
        STp[blockIdx.x * 256 + c] = acc;
    }
    if (blockIdx.x == 0 && threadIdx.x == 0) totalp[0] = 0.f;  // pre-finA (stream order)
}

// BARRIER-FREE GEMM: block = 128 rows x 1024 cols (512 blocks), but each of
// the 4 waves owns 64 rows x a PRIVATE 512-col strip with its OWN 2x8KB LDS
// double buffer (64KB total + 8KB colbuf = 72KB). No s_barrier in the loop:
// the LDS B-region is wave-private, so the only ordering needed is the
// wave's own vmcnt (stage landed) and lgkmcnt (ds_reads consumed before the
// buffer is overwritten). Waves free-run -> one wave's MFMA overlaps the
// other SIMD-resident wave's exp2 epilogue (m114). A (full K=256) pinned in
// regs as in r13; same verified 4-bit XOR chunk swizzle on both sides.
// 32 private tiles of 16 cols; same MFMA/exp totals as r13.
__global__ __launch_bounds__(256, 2) void gemm_kernel(
    const unsigned short* __restrict__ f1n, const unsigned short* __restrict__ f2n,
    float* __restrict__ rowsumexp, float* __restrict__ colsumexp)
{
    __shared__ char Bs[4][2][16 * 512];   // [wave][buf][16 B-cols x 512B] = 64KB
    __shared__ float colbuf[2][1024];     // [row-half][col]
    const int bid = blockIdx.x;
    const int bm = bid >> 3, bc = bid & 7;
    const int w = threadIdx.x >> 6, lane = threadIdx.x & 63;
    const int h = w >> 1;                 // row half (64 rows)
    const int cst = w & 1;                // private col strip (512 cols)
    const int lhi = lane >> 4, llo = lane & 15;

    // A fragments: wave's 64 rows, full K (values carry s*log2e); 128 regs.
    const char* aBase = (const char*)f1n + ((size_t)(bm * 128 + h * 64 + llo) * 512) + lhi * 16;
    short8 av[4][8];
#pragma unroll
    for (int m = 0; m < 4; ++m)
#pragma unroll
        for (int ks = 0; ks < 8; ++ks)
            av[m][ks] = *(const short8*)(aBase + (size_t)(m * 16) * 512 + ks * 64);
#pragma unroll
    for (int m = 0; m < 4; ++m)
#pragma unroll
        for (int ks = 0; ks < 8; ++ks)
            asm volatile("" : "+v"(av[m][ks]));   // pin: forbid rematerialization

    const char* bBase = (const char*)f2n + (size_t)(bc * 1024 + cst * 512) * 512;

    // Stage one 16-col B-tile (8KB) into this wave's private buffer.
    // LDS dest is linear (base + lane*16); source chunk pre-swizzled by row.
    auto stage = [&](int buf, int tile) {
        char* dst = &Bs[w][buf][0];
        const char* src = bBase + (size_t)(tile * 16) * 512;
#pragma unroll
        for (int i = 0; i < 8; ++i) {
            const int r = i * 2 + (lane >> 5);               // tile row 0..15
            const int cs = (lane & 31) ^ r;                  // pre-swizzled chunk
            __builtin_amdgcn_global_load_lds(
                (const __attribute__((address_space(1))) unsigned int*)
                    (src + (size_t)r * 512 + cs * 16),
                (__attribute__((address_space(3))) unsigned int*)
                    (dst + i * 2 * 512), 16, 0, 0);
        }
    };

    float rowpart[16];
#pragma unroll
    for (int i = 0; i < 16; ++i) rowpart[i] = 0.f;

    stage(0, 0);
    stage(1, 1);                           // 16 loads in flight

    const int sw = llo << 4;               // read-side XOR: (row & 15) << 4

    for (int t = 0; t < 32; ++t) {
        if (t < 31) {
            asm volatile("s_waitcnt vmcnt(8)" ::: "memory");   // stage(t) landed
        } else {
            asm volatile("s_waitcnt vmcnt(0)" ::: "memory");   // drain stage(31)
        }
        const char* bs = &Bs[w][t & 1][0];

        f32x4 acc[4];
#pragma unroll
        for (int m = 0; m < 4; ++m) acc[m] = (f32x4){0.f, 0.f, 0.f, 0.f};
#pragma unroll
        for (int ks = 0; ks < 8; ++ks) {
            const int kb = ks * 64 + lhi * 16;
            const short8 bv = *(const short8*)(bs + llo * 512 + (kb ^ sw));
#pragma unroll
            for (int m = 0; m < 4; ++m)
                acc[m] = __builtin_amdgcn_mfma_f32_16x16x32_bf16(av[m][ks], bv, acc[m], 0, 0, 0);
        }
        // All this tile's ds_reads are complete before refilling the buffer
        // just consumed (wave-private, so only OUR reads matter).
        asm volatile("s_waitcnt lgkmcnt(0)" ::: "memory");
        if (t < 30) stage(t & 1, t + 2);   // refill freed buffer; hides under epilogue

        float cee = 0.f;
#pragma unroll
        for (int m = 0; m < 4; ++m)
#pragma unroll
            for (int j = 0; j < 4; ++j) {
                const float e = __builtin_exp2f(acc[m][j]);
                rowpart[m * 4 + j] += e;
                cee += e;
            }
        cee += __shfl_xor(cee, 16); cee += __shfl_xor(cee, 32);   // sum over lhi
        if (lhi == 0) colbuf[h][cst * 512 + t * 16 + llo] = cee;
    }

    __syncthreads();   // first and only block barrier: colbuf visible

    // row expsums (row = h*64 + m*16 + lhi*4 + j; reduce over the 16 llo lanes)
#pragma unroll
    for (int m = 0; m < 4; ++m)
#pragma unroll
        for (int j = 0; j < 4; ++j) {
            float v = rowpart[m * 4 + j];
            v += __shfl_xor(v, 1); v += __shfl_xor(v, 2);
            v += __shfl_xor(v, 4); v += __shfl_xor(v, 8);
            if (llo == 0)
                atomicAdd(&rowsumexp[bm * 128 + h * 64 + m * 16 + lhi * 4 + j], v);
        }
    // col expsums: combine the two row-half partials
    for (int c = threadIdx.x; c < 1024; c += 256)
        atomicAdd(&colsumexp[bc * 1024 + c], colbuf[0][c] + colbuf[1][c]);
}

// finA: 32 blocks x 256 thr. (1) per-row loss terms, block-reduced, one
// atomicAdd into totalp; (2) reduce 16 of 512 STp partials into P2[g][col].
// [r16/r18/r21-verified, byte-identical]
__global__ __launch_bounds__(256) void finA_kernel(
    const float* __restrict__ rse, const float* __restrict__ cse,
    const float* __restrict__ diag, const float* __restrict__ wts,
    const float4* __restrict__ STp, float4* __restrict__ P2,
    float* __restrict__ totalp)
{
    const int g = blockIdx.x, t = threadIdx.x;
    const int i = g * 256 + t;
    const float eps = epsf(wts[i]);
    float a = __logf(rse[i]) + __logf(cse[i]) - 2.f * (1.f - eps) * diag[i];
#pragma unroll
    for (int off = 1; off < 64; off <<= 1) a += __shfl_xor(a, off);
    __shared__ float red[4];
    if ((t & 63) == 0) red[t >> 6] = a;

    float4 s = make_float4(0.f, 0.f, 0.f, 0.f);
#pragma unroll 4
    for (int j = 0; j < 16; ++j) {
        const float4 v = STp[(g * 16 + j) * 256 + t];
        s.x += v.x; s.y += v.y; s.z += v.z; s.w += v.w;
    }
    P2[g * 256 + t] = s;

    __syncthreads();
    if (t == 0) atomicAdd(totalp, red[0] + red[1] + red[2] + red[3]);
}

// fin: 1 block x 256 thr -- combine P2, per-col dot, reduce, emit scalar.
// [r16/r18/r21-verified, byte-identical]
__global__ __launch_bounds__(256) void fin_kernel(
    const float4* __restrict__ P2, const float* __restrict__ totalp,
    float* __restrict__ out)
{
    const int t = threadIdx.x;
    float4 s = make_float4(0.f, 0.f, 0.f, 0.f);
#pragma unroll 4
    for (int g = 0; g < 32; ++g) {
        const float4 v = P2[g * 256 + t];
        s.x += v.x; s.y += v.y; s.z += v.z; s.w += v.w;
    }
    float d = (s.y * s.z + s.x * s.w) * (LN2f / (float)NN);
#pragma unroll
    for (int off = 1; off < 64; off <<= 1) d += __shfl_xor(d, off);
    __shared__ float red[4];
    if ((t & 63) == 0) red[t >> 6] = d;
    __syncthreads();
    if (t == 0) {
        const float dot = red[0] + red[1] + red[2] + red[3];
        out[0] = (totalp[0] - dot) * (1.f / (2.f * (float)NN));
    }
}

extern "C" void kernel_launch(void* const* d_in, const int* in_sizes, int n_in,
                              void* d_out, int out_size, void* d_ws, size_t ws_size,
                              hipStream_t stream) {
    (void)in_sizes; (void)n_in; (void)out_size; (void)ws_size;
    const float* f1 = (const float*)d_in[0];
    const float* f2 = (const float*)d_in[1];
    const float* scale = (const float*)d_in[2];
    const float* wts = (const float*)d_in[3];
    float* out = (float*)d_out;

    char* ws = (char*)d_ws;
    unsigned short* f1n = (unsigned short*)ws;                              // 4 MB
    unsigned short* f2n = (unsigned short*)(ws + (size_t)4 * 1024 * 1024);  // 4 MB
    float* fb = (float*)(ws + (size_t)8 * 1024 * 1024);
    float* rse    = fb;                    // 8192
    float* cse    = fb + 8192;             // 8192
    float* diag   = fb + 16384;            // 8192
    float* totalp = fb + 24576;            // 1 (+pad to 16B boundary)
    float4* STp   = (float4*)(fb + 32768); // 512 x 256 float4 = 2 MB
    float4* P2    = (float4*)(fb + 32768 + 524288);  // 32 x 256 float4 = 128 KB

    nrm_kernel<<<512, 512, 0, stream>>>(f1, f2, scale, wts, f1n, f2n,
                                        diag, rse, cse, STp, totalp);
    gemm_kernel<<<512, 256, 0, stream>>>(f1n, f2n, rse, cse);
    finA_kernel<<<32, 256, 0, stream>>>(rse, cse, diag, wts, STp, P2, totalp);
    fin_kernel<<<1, 256, 0, stream>>>(P2, totalp, out);
}

// Round 23
// 69.025 us; speedup vs baseline: 1.0452x; 1.0452x over previous
//
#include <hip/hip_runtime.h>
#include <hip/hip_bf16.h>

#define NN 8192
#define DD 256
#define LOG2E 1.4426950408889634f
#define LN2f 0.6931471805599453f

typedef __attribute__((ext_vector_type(8))) short short8;
typedef __attribute__((ext_vector_type(4))) float f32x4;

__device__ __forceinline__ unsigned short f2bf(float x) {
    unsigned int u = __float_as_uint(x);
    u += 0x7fff + ((u >> 16) & 1);
    return (unsigned short)(u >> 16);
}
__device__ __forceinline__ float epsf(float w) {
    return 1.f - 0.9f / (1.f + __expf(-5.f * w));
}

// 512 blocks x 512 thr (8 waves); wave handles 2 rows serially.
// L2-normalize, fold (logit_scale*log2e) into f1n, emit bf16 + fp32 diag,
// zero rse/cse, accumulate S/T in registers, LDS-combine across 8 waves,
// STORE one float4[256] per block (no atomics). Zeroes totalp (block 0).
// [r18/r21-verified, byte-identical]
__global__ __launch_bounds__(512) void nrm_kernel(
    const float* __restrict__ f1, const float* __restrict__ f2,
    const float* __restrict__ scale_p, const float* __restrict__ wts,
    unsigned short* __restrict__ f1n, unsigned short* __restrict__ f2n,
    float* __restrict__ diag, float* __restrict__ rse, float* __restrict__ cse,
    float4* __restrict__ STp, float* __restrict__ totalp)
{
    __shared__ float4 red[8][256];
    const int w = threadIdx.x >> 6, lane = threadIdx.x & 63;
    const float s = scale_p[0];
    const int row0 = blockIdx.x * 16 + w * 2;
    float s1a[4] = {0,0,0,0}, t1a[4] = {0,0,0,0};
    float s2a[4] = {0,0,0,0}, t2a[4] = {0,0,0,0};
#pragma unroll
    for (int r = 0; r < 2; ++r) {
        const int row = row0 + r;
        const float4 a = reinterpret_cast<const float4*>(f1 + (size_t)row * DD)[lane];
        const float4 b = reinterpret_cast<const float4*>(f2 + (size_t)row * DD)[lane];
        float sa = a.x * a.x + a.y * a.y + a.z * a.z + a.w * a.w;
        float sb = b.x * b.x + b.y * b.y + b.z * b.z + b.w * b.w;
        float sab = a.x * b.x + a.y * b.y + a.z * b.z + a.w * b.w;
#pragma unroll
        for (int off = 1; off < 64; off <<= 1) {
            sa += __shfl_xor(sa, off);
            sb += __shfl_xor(sb, off);
            sab += __shfl_xor(sab, off);
        }
        const float n1 = fmaxf(sqrtf(sa), 1e-12f);
        const float n2 = fmaxf(sqrtf(sb), 1e-12f);
        const float e = epsf(wts[row]);
        if (lane == 0) { diag[row] = s * sab / (n1 * n2); rse[row] = 0.f; cse[row] = 0.f; }
        const float r1 = s * LOG2E / n1, r2 = 1.0f / n2;
        const float v0 = a.x * r1, v1 = a.y * r1, v2 = a.z * r1, v3 = a.w * r1;
        const float u0 = b.x * r2, u1 = b.y * r2, u2 = b.z * r2, u3 = b.w * r2;
        ushort4 o1, o2;
        o1.x = f2bf(v0); o1.y = f2bf(v1); o1.z = f2bf(v2); o1.w = f2bf(v3);
        o2.x = f2bf(u0); o2.y = f2bf(u1); o2.z = f2bf(u2); o2.w = f2bf(u3);
        reinterpret_cast<ushort4*>(f1n + (size_t)row * DD)[lane] = o1;
        reinterpret_cast<ushort4*>(f2n + (size_t)row * DD)[lane] = o2;
        s1a[0] += v0; s1a[1] += v1; s1a[2] += v2; s1a[3] += v3;
        t1a[0] += e * v0; t1a[1] += e * v1; t1a[2] += e * v2; t1a[3] += e * v3;
        s2a[0] += u0; s2a[1] += u1; s2a[2] += u2; s2a[3] += u3;
        t2a[0] += e * u0; t2a[1] += e * u1; t2a[2] += e * u2; t2a[3] += e * u3;
    }
#pragma unroll
    for (int k = 0; k < 4; ++k)
        red[w][lane * 4 + k] = make_float4(s1a[k], t1a[k], s2a[k], t2a[k]);
    __syncthreads();
    if (threadIdx.x < 256) {
        const int c = threadIdx.x;
        float4 acc = red[0][c];
#pragma unroll
        for (int q = 1; q < 8; ++q) {
            const float4 v = red[q][c];
            acc.x += v.x; acc.y += v.y; acc.z += v.z; acc.w += v.w;
        }
        STp[blockIdx.x * 256 + c] = acc;
    }
    if (blockIdx.x == 0 && threadIdx.x == 0) totalp[0] = 0.f;  // pre-finA (stream order)
}

// r13-verified GEMM (53.9 us, VGPR=124, 0 conflicts, no spill): block = 128
// rows x 1024 cols; A (full K=256) pinned in regs; B-tiles of 64 cols double-
// buffered in LDS; 4-bit XOR swizzle both sides; rolled loop; counted-vmcnt
// barrier scheme (never drains to 0 mid-loop). BYTE-IDENTICAL to r13/r18/r21.
__global__ __launch_bounds__(256, 2) void gemm_kernel(
    const unsigned short* __restrict__ f1n, const unsigned short* __restrict__ f2n,
    float* __restrict__ rowsumexp, float* __restrict__ colsumexp)
{
    __shared__ char Bs[2][64 * 512];
    __shared__ float colbuf[2][1024];
    const int bid = blockIdx.x;
    const int bm = bid >> 3, bc = bid & 7;
    const int w = threadIdx.x >> 6, lane = threadIdx.x & 63;
    const int wr = (w >> 1) * 64, wc = (w & 1) * 32;
    const int lhi = lane >> 4, llo = lane & 15;

    const char* aBase = (const char*)f1n + ((size_t)(bm * 128 + wr + llo) * 512) + lhi * 16;
    short8 av[4][8];
#pragma unroll
    for (int m = 0; m < 4; ++m)
#pragma unroll
        for (int ks = 0; ks < 8; ++ks)
            av[m][ks] = *(const short8*)(aBase + (size_t)(m * 16) * 512 + ks * 64);
#pragma unroll
    for (int m = 0; m < 4; ++m)
#pragma unroll
        for (int ks = 0; ks < 8; ++ks)
            asm volatile("" : "+v"(av[m][ks]));   // pin: forbid rematerialization

    const char* bBase = (const char*)f2n + (size_t)bc * 1024 * 512;

    auto stage = [&](int buf, int tile) {
#pragma unroll
        for (int i = 0; i < 8; ++i) {
            const int r = w * 16 + i * 2 + (lane >> 5);
            const int cs = (lane & 31) ^ (r & 15);          // 4-bit pre-swizzle
            __builtin_amdgcn_global_load_lds(
                (const __attribute__((address_space(1))) unsigned int*)
                    (bBase + (size_t)(tile * 64 + r) * 512 + cs * 16),
                (__attribute__((address_space(3))) unsigned int*)
                    (&Bs[buf][(w * 16 + i * 2) * 512]), 16, 0, 0);
        }
    };

    float rowpart[16];
#pragma unroll
    for (int i = 0; i < 16; ++i) rowpart[i] = 0.f;

    stage(0, 0);

    const int rb0 = wc + llo, rb1 = wc + 16 + llo;
    const int sw = llo << 4;                                // (rb & 15) << 4

    for (int t = 0; t < 16; ++t) {
        const int cur = t & 1;
        if (t < 15) {
            stage(cur ^ 1, t + 1);     // issue next-tile loads first
            asm volatile("s_waitcnt vmcnt(8)" ::: "memory");  // own stage(t) landed
        } else {
            asm volatile("s_waitcnt vmcnt(0)" ::: "memory");  // drain stage(15)
        }
        __builtin_amdgcn_s_barrier();   // all waves' stage(t) landed
        __builtin_amdgcn_sched_barrier(0);

        f32x4 acc[4][2];
#pragma unroll
        for (int m = 0; m < 4; ++m) {
            acc[m][0] = (f32x4){0.f, 0.f, 0.f, 0.f};
            acc[m][1] = (f32x4){0.f, 0.f, 0.f, 0.f};
        }
        const char* bs = Bs[cur];
#pragma unroll
        for (int ks = 0; ks < 8; ++ks) {
            const int kb = ks * 64 + lhi * 16;
            const short8 bv0 = *(const short8*)(bs + rb0 * 512 + (kb ^ sw));
            const short8 bv1 = *(const short8*)(bs + rb1 * 512 + (kb ^ sw));
#pragma unroll
            for (int m = 0; m < 4; ++m) {
                acc[m][0] = __builtin_amdgcn_mfma_f32_16x16x32_bf16(av[m][ks], bv0, acc[m][0], 0, 0, 0);
                acc[m][1] = __builtin_amdgcn_mfma_f32_16x16x32_bf16(av[m][ks], bv1, acc[m][1], 0, 0, 0);
            }
        }

        float cee0 = 0.f, cee1 = 0.f;
#pragma unroll
        for (int m = 0; m < 4; ++m)
#pragma unroll
            for (int j = 0; j < 4; ++j) {
                const float e0 = __builtin_exp2f(acc[m][0][j]);
                const float e1 = __builtin_exp2f(acc[m][1][j]);
                rowpart[m * 4 + j] += e0 + e1;
                cee0 += e0; cee1 += e1;
            }
        cee0 += __shfl_xor(cee0, 16); cee0 += __shfl_xor(cee0, 32);
        cee1 += __shfl_xor(cee1, 16); cee1 += __shfl_xor(cee1, 32);
        if (lhi == 0) {
            colbuf[w >> 1][t * 64 + wc + llo] = cee0;
            colbuf[w >> 1][t * 64 + wc + 16 + llo] = cee1;
        }
        __builtin_amdgcn_s_barrier();   // reads of Bs[cur] done; stage may overwrite
    }

    __syncthreads();   // full drain: colbuf writes visible to all waves

#pragma unroll
    for (int m = 0; m < 4; ++m)
#pragma unroll
        for (int j = 0; j < 4; ++j) {
            float v = rowpart[m * 4 + j];
            v += __shfl_xor(v, 1); v += __shfl_xor(v, 2);
            v += __shfl_xor(v, 4); v += __shfl_xor(v, 8);
            if (llo == 0)
                atomicAdd(&rowsumexp[bm * 128 + wr + m * 16 + lhi * 4 + j], v);
        }
    for (int c = threadIdx.x; c < 1024; c += 256)
        atomicAdd(&colsumexp[bc * 1024 + c], colbuf[0][c] + colbuf[1][c]);
}

// finA: 32 blocks x 256 thr. (1) per-row loss terms, block-reduced, one
// atomicAdd into totalp; (2) reduce 16 of 512 STp partials into P2[g][col].
// [r16/r18/r21-verified, byte-identical]
__global__ __launch_bounds__(256) void finA_kernel(
    const float* __restrict__ rse, const float* __restrict__ cse,
    const float* __restrict__ diag, const float* __restrict__ wts,
    const float4* __restrict__ STp, float4* __restrict__ P2,
    float* __restrict__ totalp)
{
    const int g = blockIdx.x, t = threadIdx.x;
    const int i = g * 256 + t;
    const float eps = epsf(wts[i]);
    float a = __logf(rse[i]) + __logf(cse[i]) - 2.f * (1.f - eps) * diag[i];
#pragma unroll
    for (int off = 1; off < 64; off <<= 1) a += __shfl_xor(a, off);
    __shared__ float red[4];
    if ((t & 63) == 0) red[t >> 6] = a;

    float4 s = make_float4(0.f, 0.f, 0.f, 0.f);
#pragma unroll 4
    for (int j = 0; j < 16; ++j) {
        const float4 v = STp[(g * 16 + j) * 256 + t];
        s.x += v.x; s.y += v.y; s.z += v.z; s.w += v.w;
    }
    P2[g * 256 + t] = s;

    __syncthreads();
    if (t == 0) atomicAdd(totalp, red[0] + red[1] + red[2] + red[3]);
}

// fin: 1 block x 256 thr -- combine P2, per-col dot, reduce, emit scalar.
// [r16/r18/r21-verified, byte-identical]
__global__ __launch_bounds__(256) void fin_kernel(
    const float4* __restrict__ P2, const float* __restrict__ totalp,
    float* __restrict__ out)
{
    const int t = threadIdx.x;
    float4 s = make_float4(0.f, 0.f, 0.f, 0.f);
#pragma unroll 4
    for (int g = 0; g < 32; ++g) {
        const float4 v = P2[g * 256 + t];
        s.x += v.x; s.y += v.y; s.z += v.z; s.w += v.w;
    }
    float d = (s.y * s.z + s.x * s.w) * (LN2f / (float)NN);
#pragma unroll
    for (int off = 1; off < 64; off <<= 1) d += __shfl_xor(d, off);
    __shared__ float red[4];
    if ((t & 63) == 0) red[t >> 6] = d;
    __syncthreads();
    if (t == 0) {
        const float dot = red[0] + red[1] + red[2] + red[3];
        out[0] = (totalp[0] - dot) * (1.f / (2.f * (float)NN));
    }
}

extern "C" void kernel_launch(void* const* d_in, const int* in_sizes, int n_in,
                              void* d_out, int out_size, void* d_ws, size_t ws_size,
                              hipStream_t stream) {
    (void)in_sizes; (void)n_in; (void)out_size; (void)ws_size;
    const float* f1 = (const float*)d_in[0];
    const float* f2 = (const float*)d_in[1];
    const float* scale = (const float*)d_in[2];
    const float* wts = (const float*)d_in[3];
    float* out = (float*)d_out;

    char* ws = (char*)d_ws;
    unsigned short* f1n = (unsigned short*)ws;                              // 4 MB
    unsigned short* f2n = (unsigned short*)(ws + (size_t)4 * 1024 * 1024);  // 4 MB
    float* fb = (float*)(ws + (size_t)8 * 1024 * 1024);
    float* rse    = fb;                    // 8192
    float* cse    = fb + 8192;             // 8192
    float* diag   = fb + 16384;            // 8192
    float* totalp = fb + 24576;            // 1 (+pad to 16B boundary)
    float4* STp   = (float4*)(fb + 32768); // 512 x 256 float4 = 2 MB
    float4* P2    = (float4*)(fb + 32768 + 524288);  // 32 x 256 float4 = 128 KB

    nrm_kernel<<<512, 512, 0, stream>>>(f1, f2, scale, wts, f1n, f2n,
                                        diag, rse, cse, STp, totalp);
    gemm_kernel<<<512, 256, 0, stream>>>(f1n, f2n, rse, cse);
    finA_kernel<<<32, 256, 0, stream>>>(rse, cse, diag, wts, STp, P2, totalp);
    fin_kernel<<<1, 256, 0, stream>>>(P2, totalp, out);
}